// Round 3
// baseline (319.937 us; speedup 1.0000x reference)
//
#include <hip/hip_runtime.h>
#include <stdint.h>

#define MDIM 8192
#define NDIM 1536
#define KDIM 3072

#define BM 128
#define BN 128
#define BK 32

typedef unsigned short u16;
typedef float  f32x4  __attribute__((ext_vector_type(4)));
typedef __bf16 bf16x8 __attribute__((ext_vector_type(8)));

__device__ __forceinline__ u16 f2bf(float f) {
    union { float f; unsigned int u; } v; v.f = f;
    unsigned int u = v.u;
    return (u16)((u + 0x7fffu + ((u >> 16) & 1u)) >> 16);  // RNE
}

// ------- prep: Bt[n][k] = bf16(mask[n][k] * w[k][n]) -------
__global__ void make_b_kernel(const float* __restrict__ w, const float* __restrict__ mask,
                              u16* __restrict__ Bt) {
    __shared__ float sw[64][65];
    const int t  = threadIdx.x;
    const int kb = blockIdx.x % (KDIM / 64);
    const int nb = blockIdx.x / (KDIM / 64);
    const int k0 = kb * 64, n0 = nb * 64;
    {
        const int c4 = t & 15;
        const int r  = t >> 4;
#pragma unroll
        for (int rr = 0; rr < 4; ++rr) {
            int row = rr * 16 + r;
            float4 v = *(const float4*)&w[(size_t)(k0 + row) * NDIM + n0 + c4 * 4];
            sw[row][c4 * 4 + 0] = v.x;
            sw[row][c4 * 4 + 1] = v.y;
            sw[row][c4 * 4 + 2] = v.z;
            sw[row][c4 * 4 + 3] = v.w;
        }
    }
    __syncthreads();
    {
        const int n  = t >> 2;
        const int ks = (t & 3) * 16;
#pragma unroll
        for (int j = 0; j < 4; ++j) {
            int k = ks + j * 4;
            float4 mv = *(const float4*)&mask[(size_t)(n0 + n) * KDIM + k0 + k];
            ushort4 o;
            o.x = f2bf(mv.x * sw[k + 0][n]);
            o.y = f2bf(mv.y * sw[k + 1][n]);
            o.z = f2bf(mv.z * sw[k + 2][n]);
            o.w = f2bf(mv.w * sw[k + 3][n]);
            *(ushort4*)&Bt[(size_t)(n0 + n) * KDIM + k0 + k] = o;
        }
    }
}

// ---------------- GEMM: C[m][n] = sum_k x[m][k]*Bt[n][k] + bias[n] ----------------
// A is read DIRECTLY as fp32 (no xb prep pass): global_load_lds w=16 stages 4 floats/lane
// into a 16 KB fp32 sA; fragments are cvt'd to bf16 in-register before MFMA.
// A-swizzle: fp32 row = 128 B = 8 x 16B chunks; chunk c of row r lives at slot c^(r&7)
//   -> frag reads hit each 16B-position with exactly 8 of 64 lanes (uniform, conflict-free).
// B path unchanged from R2 (bf16, 4-chunk XOR swizzle, measured 0 conflicts).
__device__ __forceinline__ void gload_lds16(const void* g, void* l) {
    __builtin_amdgcn_global_load_lds(
        (const __attribute__((address_space(1))) unsigned int*)g,
        (__attribute__((address_space(3))) unsigned int*)l, 16, 0, 0);
}

__global__ void gemm_kernel(const float* __restrict__ X,  // [M][K] fp32
                            const u16* __restrict__ B,    // [N][K] bf16
                            const float* __restrict__ bias,
                            float* __restrict__ C) {      // [M][N] fp32
    __shared__ float sA[BM * BK];  // 16 KiB fp32
    __shared__ u16   sB[BN * BK];  //  8 KiB bf16

    const int tid  = threadIdx.x;
    const int wave = tid >> 6;
    const int lane = tid & 63;

    const int bx = blockIdx.x % (NDIM / BN);
    const int by = blockIdx.x / (NDIM / BN);
    const int m0 = by * BM, n0 = bx * BN;

    // ---- A staging: 4 wave-instrs, instr j covers rows [wave*32+j*8, +8) ----
    // lane l: row = wave*32 + j*8 + (l>>3); global chunk c = (l&7)^(l>>3); LDS slot = l&7.
    const int arow  = lane >> 3;                       // 0..7
    const int acol  = ((lane & 7) ^ (lane >> 3)) * 4;  // float offset of 16B chunk

    // ---- B staging: as R2 (rows wave*16+(l>>2) and +64; chunk (l&3)^((l>>3)&3)) ----
    const int bsrow = lane >> 2;
    const int bscol = ((lane & 3) ^ ((lane >> 3) & 3)) * 8;

    const int wm = (wave >> 1) * 64;
    const int wn = (wave & 1) * 64;
    const int fr = lane & 15;
    const int fq = lane >> 4;
    const int fswB = (fq ^ ((fr >> 1) & 3)) * 8;       // B chunk swizzle (4 chunks/row)
    const int s0   = ((2 * fq) ^ (fr & 7)) * 4;        // A slot for k=fq*8..+3 (floats)
    const int s1   = (((2 * fq) | 1) ^ (fr & 7)) * 4;  // A slot for k=fq*8+4..+7

    f32x4 acc[4][4] = {};

    const float* gA0 = X + (size_t)(m0 + wave * 32 + arow) * KDIM + acol;
    const u16*   gB0 = B + (size_t)(n0 + wave * 16 + bsrow) * KDIM + bscol;
    float* lA0 = &sA[(wave * 32 +  0) * BK];
    float* lA1 = &sA[(wave * 32 +  8) * BK];
    float* lA2 = &sA[(wave * 32 + 16) * BK];
    float* lA3 = &sA[(wave * 32 + 24) * BK];
    u16* lB0 = &sB[(wave * 16) * BK];
    u16* lB1 = &sB[(wave * 16 + 64) * BK];

    for (int k0 = 0; k0 < KDIM; k0 += BK) {
        __syncthreads();
        gload_lds16(gA0 + k0,                      lA0);
        gload_lds16(gA0 + k0 + (size_t) 8 * KDIM,  lA1);
        gload_lds16(gA0 + k0 + (size_t)16 * KDIM,  lA2);
        gload_lds16(gA0 + k0 + (size_t)24 * KDIM,  lA3);
        gload_lds16(gB0 + k0,                      lB0);
        gload_lds16(gB0 + k0 + (size_t)64 * KDIM,  lB1);
        __syncthreads();

        bf16x8 af[4], bfv[4];
#pragma unroll
        for (int mt = 0; mt < 4; ++mt) {
            const int r = wm + mt * 16 + fr;          // r&7 == fr&7
            f32x4 lo = *(const f32x4*)&sA[r * BK + s0];
            f32x4 hi = *(const f32x4*)&sA[r * BK + s1];
            bf16x8 a;
#pragma unroll
            for (int e = 0; e < 4; ++e) { a[e] = (__bf16)lo[e]; a[4 + e] = (__bf16)hi[e]; }
            af[mt] = a;
        }
#pragma unroll
        for (int nt = 0; nt < 4; ++nt)
            bfv[nt] = *(const bf16x8*)&sB[(wn + nt * 16 + fr) * BK + fswB];
#pragma unroll
        for (int mt = 0; mt < 4; ++mt)
#pragma unroll
            for (int nt = 0; nt < 4; ++nt)
                acc[mt][nt] = __builtin_amdgcn_mfma_f32_16x16x32_bf16(
                    af[mt], bfv[nt], acc[mt][nt], 0, 0, 0);
    }

    // epilogue: C/D layout col = lane&15, row = (lane>>4)*4 + reg  [m89-verified]
#pragma unroll
    for (int nt = 0; nt < 4; ++nt) {
        int n = n0 + wn + nt * 16 + fr;
        float bv = bias[n];
#pragma unroll
        for (int mt = 0; mt < 4; ++mt) {
            int m = m0 + wm + mt * 16 + fq * 4;
#pragma unroll
            for (int r = 0; r < 4; ++r)
                C[(size_t)(m + r) * NDIM + n] = acc[mt][nt][r] + bv;
        }
    }
}

extern "C" void kernel_launch(void* const* d_in, const int* in_sizes, int n_in,
                              void* d_out, int out_size, void* d_ws, size_t ws_size,
                              hipStream_t stream) {
    const float* x    = (const float*)d_in[0];   // [8192][3072]
    const float* w    = (const float*)d_in[1];   // [3072][1536]
    const float* bias = (const float*)d_in[2];   // [1536]
    const float* mask = (const float*)d_in[3];   // [1536][3072]
    float* out = (float*)d_out;                  // [8192][1536]

    u16* Bt = (u16*)d_ws;                        // 1536*3072*2 = 9437184 B only

    make_b_kernel<<<(KDIM / 64) * (NDIM / 64), 256, 0, stream>>>(w, mask, Bt);
    gemm_kernel<<<(MDIM / BM) * (NDIM / BN), 256, 0, stream>>>(x, Bt, bias, out);
}

// Round 4
// 283.902 us; speedup vs baseline: 1.1269x; 1.1269x over previous
//
#include <hip/hip_runtime.h>
#include <stdint.h>

#define MDIM 8192
#define NDIM 1536
#define KDIM 3072

#define BM 128
#define BN 128
#define BK 64            // two 32-k planes, each in the R2-proven 64B-row layout

#define NMB ((KDIM / 64) * (NDIM / 64))
#define NCVT ((MDIM * KDIM / 4) / 256)

typedef unsigned short u16;
typedef float  f32x4  __attribute__((ext_vector_type(4)));
typedef __bf16 bf16x8 __attribute__((ext_vector_type(8)));

__device__ __forceinline__ u16 f2bf(float f) {
    union { float f; unsigned int u; } v; v.f = f;
    unsigned int u = v.u;
    return (u16)((u + 0x7fffu + ((u >> 16) & 1u)) >> 16);  // RNE
}

// ---------------- fused prep: make_b blocks, then cvt_x blocks ----------------
__global__ void prep_kernel(const float* __restrict__ w, const float* __restrict__ mask,
                            u16* __restrict__ Bt,
                            const float4* __restrict__ x, ushort4* __restrict__ xb) {
    const int t = threadIdx.x;
    if (blockIdx.x < NMB) {
        __shared__ float sw[64][65];
        const int kb = blockIdx.x % (KDIM / 64);
        const int nb = blockIdx.x / (KDIM / 64);
        const int k0 = kb * 64, n0 = nb * 64;
        {
            const int c4 = t & 15;
            const int r  = t >> 4;
#pragma unroll
            for (int rr = 0; rr < 4; ++rr) {
                int row = rr * 16 + r;
                float4 v = *(const float4*)&w[(size_t)(k0 + row) * NDIM + n0 + c4 * 4];
                sw[row][c4 * 4 + 0] = v.x;
                sw[row][c4 * 4 + 1] = v.y;
                sw[row][c4 * 4 + 2] = v.z;
                sw[row][c4 * 4 + 3] = v.w;
            }
        }
        __syncthreads();
        {
            const int n  = t >> 2;
            const int ks = (t & 3) * 16;
#pragma unroll
            for (int j = 0; j < 4; ++j) {
                int k = ks + j * 4;
                float4 mv = *(const float4*)&mask[(size_t)(n0 + n) * KDIM + k0 + k];
                ushort4 o;
                o.x = f2bf(mv.x * sw[k + 0][n]);
                o.y = f2bf(mv.y * sw[k + 1][n]);
                o.z = f2bf(mv.z * sw[k + 2][n]);
                o.w = f2bf(mv.w * sw[k + 3][n]);
                *(ushort4*)&Bt[(size_t)(n0 + n) * KDIM + k0 + k] = o;
            }
        }
    } else {
        int i = (blockIdx.x - NMB) * 256 + t;
        float4 v = x[i];
        ushort4 o;
        o.x = f2bf(v.x); o.y = f2bf(v.y); o.z = f2bf(v.z); o.w = f2bf(v.w);
        xb[i] = o;
    }
}

// ---------------- GEMM: C[m][n] = sum_k A[m][k]*Bt[n][k] + bias[n] ----------------
// BK=64 as two k-planes of 32. Each plane: rows of 64 B (32 bf16) with the R2-measured
// conflict-free XOR chunk swizzle: 16B chunk (row r, c) at slot 4r + (c ^ ((r>>1)&3));
// global_load_lds dest is lane-linear, so the swizzle is applied to the global source.
// Halves the barrier/vmcnt-drain count vs BK=32 (96 -> 48 iterations).
__device__ __forceinline__ void gload_lds16(const void* g, void* l) {
    __builtin_amdgcn_global_load_lds(
        (const __attribute__((address_space(1))) unsigned int*)g,
        (__attribute__((address_space(3))) unsigned int*)l, 16, 0, 0);
}

#define PLANE (128 * 32)   // bf16 elements per k-plane

__global__ void gemm_kernel(const u16* __restrict__ A,   // [M][K] bf16
                            const u16* __restrict__ B,   // [N][K] bf16
                            const float* __restrict__ bias,
                            float* __restrict__ C) {     // [M][N] fp32
    __shared__ u16 sA[2 * PLANE];  // 16 KiB
    __shared__ u16 sB[2 * PLANE];  // 16 KiB

    const int tid  = threadIdx.x;
    const int wave = tid >> 6;
    const int lane = tid & 63;

    const int bx = blockIdx.x % (NDIM / BN);
    const int by = blockIdx.x / (NDIM / BN);
    const int m0 = by * BM, n0 = bx * BN;

    // staging (per plane, identical to R2): lane l -> row l>>2, global chunk (l&3)^((l>>3)&3)
    const int srow = lane >> 2;
    const int scol = ((lane & 3) ^ ((lane >> 3) & 3)) * 8;

    const int wm = (wave >> 1) * 64;
    const int wn = (wave & 1) * 64;
    const int fr = lane & 15;
    const int fq = lane >> 4;
    const int fsw = (fq ^ ((fr >> 1) & 3)) * 8;   // R2-proven swizzled chunk offset

    f32x4 acc[4][4] = {};

    const u16* gA0 = A + (size_t)(m0 + wave * 16 + srow) * KDIM + scol;
    const u16* gB0 = B + (size_t)(n0 + wave * 16 + srow) * KDIM + scol;
    // LDS bases: [plane][rowgroup]; wave w stages rows [w*16, w*16+16) and +64 of each plane
    u16* lA00 = &sA[0 * PLANE + (wave * 16) * 32];
    u16* lA01 = &sA[0 * PLANE + (wave * 16 + 64) * 32];
    u16* lA10 = &sA[1 * PLANE + (wave * 16) * 32];
    u16* lA11 = &sA[1 * PLANE + (wave * 16 + 64) * 32];
    u16* lB00 = &sB[0 * PLANE + (wave * 16) * 32];
    u16* lB01 = &sB[0 * PLANE + (wave * 16 + 64) * 32];
    u16* lB10 = &sB[1 * PLANE + (wave * 16) * 32];
    u16* lB11 = &sB[1 * PLANE + (wave * 16 + 64) * 32];

    for (int k0 = 0; k0 < KDIM; k0 += BK) {
        __syncthreads();
        gload_lds16(gA0 + k0,                           lA00);
        gload_lds16(gA0 + k0 + (size_t)64 * KDIM,       lA01);
        gload_lds16(gA0 + k0 + 32,                      lA10);
        gload_lds16(gA0 + k0 + 32 + (size_t)64 * KDIM,  lA11);
        gload_lds16(gB0 + k0,                           lB00);
        gload_lds16(gB0 + k0 + (size_t)64 * KDIM,       lB01);
        gload_lds16(gB0 + k0 + 32,                      lB10);
        gload_lds16(gB0 + k0 + 32 + (size_t)64 * KDIM,  lB11);
        __syncthreads();

#pragma unroll
        for (int h = 0; h < 2; ++h) {
            const u16* pA = &sA[h * PLANE];
            const u16* pB = &sB[h * PLANE];
            bf16x8 af[4], bfv[4];
#pragma unroll
            for (int mt = 0; mt < 4; ++mt)
                af[mt] = *(const bf16x8*)&pA[(wm + mt * 16 + fr) * 32 + fsw];
#pragma unroll
            for (int nt = 0; nt < 4; ++nt)
                bfv[nt] = *(const bf16x8*)&pB[(wn + nt * 16 + fr) * 32 + fsw];
#pragma unroll
            for (int mt = 0; mt < 4; ++mt)
#pragma unroll
                for (int nt = 0; nt < 4; ++nt)
                    acc[mt][nt] = __builtin_amdgcn_mfma_f32_16x16x32_bf16(
                        af[mt], bfv[nt], acc[mt][nt], 0, 0, 0);
        }
    }

    // epilogue: C/D layout col = lane&15, row = (lane>>4)*4 + reg  [m89-verified]
#pragma unroll
    for (int nt = 0; nt < 4; ++nt) {
        int n = n0 + wn + nt * 16 + fr;
        float bv = bias[n];
#pragma unroll
        for (int mt = 0; mt < 4; ++mt) {
            int m = m0 + wm + mt * 16 + fq * 4;
#pragma unroll
            for (int r = 0; r < 4; ++r)
                C[(size_t)(m + r) * NDIM + n] = acc[mt][nt][r] + bv;
        }
    }
}

extern "C" void kernel_launch(void* const* d_in, const int* in_sizes, int n_in,
                              void* d_out, int out_size, void* d_ws, size_t ws_size,
                              hipStream_t stream) {
    const float* x    = (const float*)d_in[0];   // [8192][3072]
    const float* w    = (const float*)d_in[1];   // [3072][1536]
    const float* bias = (const float*)d_in[2];   // [1536]
    const float* mask = (const float*)d_in[3];   // [1536][3072]
    float* out = (float*)d_out;                  // [8192][1536]

    u16* xb = (u16*)d_ws;                                   // 50331648 B
    u16* Bt = (u16*)((char*)d_ws + (size_t)50331648);       //  9437184 B

    prep_kernel<<<NMB + NCVT, 256, 0, stream>>>(w, mask, Bt, (const float4*)x, (ushort4*)xb);
    gemm_kernel<<<(MDIM / BM) * (NDIM / BN), 256, 0, stream>>>(xb, Bt, bias, out);
}